// Round 1
// baseline (42048.785 us; speedup 1.0000x reference)
//
#include <hip/hip_runtime.h>
#include <hip/hip_bf16.h>
#include <math.h>

#define NL 2
#define PD 768
#define QD 768
#define HD 768
#define AD 768
#define BS 16
#define TT 128
#define TQN 128
#define H4 3072
#define EPSF 1e-6f

__device__ __forceinline__ float fsigmoid(float x){ return 1.0f/(1.0f + __expf(-x)); }
__device__ __forceinline__ float ftanh(float x){
    float ax = fabsf(x);
    if (ax > 15.0f) return copysignf(1.0f, x);
    float e = __expf(2.0f*x);
    return (e - 1.0f) / (e + 1.0f);
}

__global__ void k_zero(float* p, int n){
    int i = blockIdx.x*blockDim.x + threadIdx.x;
    if (i < n) p[i] = 0.f;
}

__global__ void k_copytail(const float* __restrict__ src, float* __restrict__ dst, int n){
    int i = blockIdx.x*blockDim.x + threadIdx.x;
    if (i < n) dst[i] = src[i];
}

// ---------------------------------------------------------------------------
// Generic precompute matmul: C[r, n] = sum_k A[r*768 + k] * W[k*ldw + n]
// rows tiled by 16 (gridDim.y), cols by 64 (gridDim.x). 256 threads.
// thread: 1 row x 4 cols. A staged in LDS (row-padded to 772 to avoid bank conflicts).
// ---------------------------------------------------------------------------
__global__ __launch_bounds__(256) void k_mm_pre(
    const float* __restrict__ Ain, const float* __restrict__ W,
    float* __restrict__ C, int ldw, int ncols)
{
    __shared__ float Ash[16][772];
    int rowbase = blockIdx.y*16;
    for (int r = 0; r < 16; r++)
        for (int i = threadIdx.x; i < 768; i += 256)
            Ash[r][i] = Ain[(size_t)(rowbase + r)*768 + i];
    __syncthreads();
    int lane = threadIdx.x & 63;
    int colq = lane & 15, rsub = lane >> 4, wq = threadIdx.x >> 6;
    int r = wq*4 + rsub;
    int col = blockIdx.x*64 + colq*4;
    float4 acc = {0.f,0.f,0.f,0.f};
    const float* Wc = W + col;
    for (int k = 0; k < 768; k += 4){
        float4 a4 = *(const float4*)&Ash[r][k];
        float4 w0 = *(const float4*)(Wc + (size_t)(k+0)*ldw);
        float4 w1 = *(const float4*)(Wc + (size_t)(k+1)*ldw);
        float4 w2 = *(const float4*)(Wc + (size_t)(k+2)*ldw);
        float4 w3 = *(const float4*)(Wc + (size_t)(k+3)*ldw);
        acc.x += a4.x*w0.x + a4.y*w1.x + a4.z*w2.x + a4.w*w3.x;
        acc.y += a4.x*w0.y + a4.y*w1.y + a4.z*w2.y + a4.w*w3.y;
        acc.z += a4.x*w0.z + a4.y*w1.z + a4.z*w2.z + a4.w*w3.z;
        acc.w += a4.x*w0.w + a4.y*w1.w + a4.z*w2.w + a4.w*w3.w;
    }
    *(float4*)(C + (size_t)(rowbase + r)*ncols + col) = acc;
}

// ---------------------------------------------------------------------------
// Stage 1 (per t,d): s_A = h@Wr + b_att (+pWp0[t] if d==0)   -> s_buf
//                    s_B = cur@Wp (d==1 only)                -> s_buf2
//                    wh_raw = h@W_hh
//                    cw_raw = cur@W_ih[0:768]  (d==1 only)
// role-partitioned heterogeneous blocks. 256 threads, 64 cols x 16 rows.
// ---------------------------------------------------------------------------
__global__ __launch_bounds__(256) void k_stage1(
    const float* __restrict__ hd, const float* __restrict__ cur,
    const float* __restrict__ Wr, const float* __restrict__ Wp,
    const float* __restrict__ Whh, const float* __restrict__ Wih,
    const float* __restrict__ batt, const float* __restrict__ pWp0,
    int t, int d,
    float* __restrict__ s_buf, float* __restrict__ s_buf2,
    float* __restrict__ wh_raw, float* __restrict__ cw_raw)
{
    __shared__ float Ash[16][772];
    int bid = blockIdx.x;
    int role, jt;
    if (d == 0){
        if (bid < 12){ role = 0; jt = bid; } else { role = 2; jt = bid - 12; }
    } else {
        if (bid < 12){ role = 0; jt = bid; }
        else if (bid < 24){ role = 1; jt = bid - 12; }
        else if (bid < 72){ role = 2; jt = bid - 24; }
        else { role = 3; jt = bid - 72; }
    }
    const float* Aop = (role == 1 || role == 3) ? cur : hd;
    for (int r = 0; r < 16; r++)
        for (int i = threadIdx.x; i < 768; i += 256)
            Ash[r][i] = Aop[r*768 + i];
    __syncthreads();

    int lane = threadIdx.x & 63;
    int colq = lane & 15, rsub = lane >> 4, wq = threadIdx.x >> 6;
    int r = wq*4 + rsub;
    int col = jt*64 + colq*4;

    const float* W; int ldw;
    if (role == 0){ W = Wr;  ldw = 768;  }
    else if (role == 1){ W = Wp;  ldw = 768;  }
    else if (role == 2){ W = Whh; ldw = 3072; }
    else { W = Wih; ldw = 3072; }

    float4 acc = {0.f,0.f,0.f,0.f};
    if (role == 0){
        acc.x = batt[col]; acc.y = batt[col+1]; acc.z = batt[col+2]; acc.w = batt[col+3];
        if (d == 0){
            const float* pp = pWp0 + (size_t)(r*TT + t)*768 + col;
            acc.x += pp[0]; acc.y += pp[1]; acc.z += pp[2]; acc.w += pp[3];
        }
    }
    const float* Wc = W + col;
    for (int k = 0; k < 768; k += 4){
        float4 a4 = *(const float4*)&Ash[r][k];
        float4 w0 = *(const float4*)(Wc + (size_t)(k+0)*ldw);
        float4 w1 = *(const float4*)(Wc + (size_t)(k+1)*ldw);
        float4 w2 = *(const float4*)(Wc + (size_t)(k+2)*ldw);
        float4 w3 = *(const float4*)(Wc + (size_t)(k+3)*ldw);
        acc.x += a4.x*w0.x + a4.y*w1.x + a4.z*w2.x + a4.w*w3.x;
        acc.y += a4.x*w0.y + a4.y*w1.y + a4.z*w2.y + a4.w*w3.y;
        acc.z += a4.x*w0.z + a4.y*w1.z + a4.z*w2.z + a4.w*w3.z;
        acc.w += a4.x*w0.w + a4.y*w1.w + a4.z*w2.w + a4.w*w3.w;
    }
    float* Obuf = (role == 0) ? s_buf : (role == 1) ? s_buf2 : (role == 2) ? wh_raw : cw_raw;
    int ncols = (role <= 1) ? 768 : 3072;
    *(float4*)(Obuf + (size_t)r*ncols + col) = acc;
}

// ---------------------------------------------------------------------------
// Stage 2: attention, one block per batch element b. 1024 threads.
// scores[sq] = sum_a tanh(qWq[b,sq,a] + s[a]) * w_att[a]; masked softmax;
// weighted[b,:] = alpha @ input_q[b]
// ---------------------------------------------------------------------------
__global__ __launch_bounds__(1024) void k_attn(
    const float* __restrict__ s_buf, const float* __restrict__ s_buf2, int use2,
    const float* __restrict__ qWq_d, const float* __restrict__ w_att_d,
    const float* __restrict__ mask_q, const float* __restrict__ input_q,
    float* __restrict__ weighted)
{
    __shared__ float s_sh[768], wa_sh[768], sc_sh[128], al_sh[128], red_sh[2];
    int b = blockIdx.x, tid = threadIdx.x;
    if (tid < 768){
        float v = s_buf[b*768 + tid];
        if (use2) v += s_buf2[b*768 + tid];
        s_sh[tid] = v;
        wa_sh[tid] = w_att_d[tid];
    }
    __syncthreads();

    int sq = tid >> 3, oct = tid & 7;
    const float* qrow = qWq_d + (size_t)(b*TQN + sq)*768;
    float part = 0.f;
    #pragma unroll 4
    for (int i = 0; i < 24; i++){
        int a = (oct + 8*i)*4;
        float4 q  = *(const float4*)(qrow + a);
        float4 s4 = *(const float4*)(s_sh + a);
        float4 w4 = *(const float4*)(wa_sh + a);
        part += ftanh(q.x + s4.x)*w4.x + ftanh(q.y + s4.y)*w4.y
              + ftanh(q.z + s4.z)*w4.z + ftanh(q.w + s4.w)*w4.w;
    }
    part += __shfl_down(part, 4, 8);
    part += __shfl_down(part, 2, 8);
    part += __shfl_down(part, 1, 8);
    if (oct == 0){
        sc_sh[sq] = (mask_q[b*TQN + sq] > 0.f) ? part : -1e9f;
    }
    __syncthreads();
    if (tid < 64){
        float m = fmaxf(sc_sh[tid], sc_sh[tid + 64]);
        #pragma unroll
        for (int off = 32; off; off >>= 1) m = fmaxf(m, __shfl_xor(m, off));
        if (tid == 0) red_sh[0] = m;
    }
    __syncthreads();
    float mx = red_sh[0];
    if (tid < 128) al_sh[tid] = __expf(sc_sh[tid] - mx);
    __syncthreads();
    if (tid < 64){
        float s = al_sh[tid] + al_sh[tid + 64];
        #pragma unroll
        for (int off = 32; off; off >>= 1) s += __shfl_xor(s, off);
        if (tid == 0) red_sh[1] = 1.0f / s;
    }
    __syncthreads();
    float inv = red_sh[1];
    if (tid < 768){
        float acc = 0.f;
        const float* iq = input_q + (size_t)b*TQN*768 + tid;
        #pragma unroll 4
        for (int sq2 = 0; sq2 < 128; sq2++) acc += al_sh[sq2]*iq[(size_t)sq2*768];
        weighted[b*768 + tid] = acc*inv;
    }
}

// ---------------------------------------------------------------------------
// Stage 3: wi_raw = curWihsrc + weighted @ W_ih[768:1536]
// 48 blocks x 256 threads, 64 cols x 16 rows each.
// ---------------------------------------------------------------------------
__global__ __launch_bounds__(256) void k_stage3(
    const float* __restrict__ weighted, const float* __restrict__ Wih,
    const float* __restrict__ cursrc, int srcIsP, int t,
    float* __restrict__ wi_raw)
{
    __shared__ float Ash[16][772];
    for (int r = 0; r < 16; r++)
        for (int i = threadIdx.x; i < 768; i += 256)
            Ash[r][i] = weighted[r*768 + i];
    __syncthreads();

    int lane = threadIdx.x & 63;
    int colq = lane & 15, rsub = lane >> 4, wq = threadIdx.x >> 6;
    int r = wq*4 + rsub;
    int col = blockIdx.x*64 + colq*4;

    float4 acc;
    if (srcIsP){
        acc = *(const float4*)(cursrc + (size_t)(r*TT + t)*3072 + col);
    } else {
        acc = *(const float4*)(cursrc + (size_t)r*3072 + col);
    }
    const float* Wc = Wih + (size_t)768*3072 + col;
    for (int k = 0; k < 768; k += 4){
        float4 a4 = *(const float4*)&Ash[r][k];
        float4 w0 = *(const float4*)(Wc + (size_t)(k+0)*3072);
        float4 w1 = *(const float4*)(Wc + (size_t)(k+1)*3072);
        float4 w2 = *(const float4*)(Wc + (size_t)(k+2)*3072);
        float4 w3 = *(const float4*)(Wc + (size_t)(k+3)*3072);
        acc.x += a4.x*w0.x + a4.y*w1.x + a4.z*w2.x + a4.w*w3.x;
        acc.y += a4.x*w0.y + a4.y*w1.y + a4.z*w2.y + a4.w*w3.y;
        acc.z += a4.x*w0.z + a4.y*w1.z + a4.z*w2.z + a4.w*w3.z;
        acc.w += a4.x*w0.w + a4.y*w1.w + a4.z*w2.w + a4.w*w3.w;
    }
    *(float4*)(wi_raw + (size_t)r*3072 + col) = acc;
}

// ---------------------------------------------------------------------------
// Stage 4: LN(wi), LN(wh), gates, c/h update, LN_c. One block per b, 512 thr.
// ---------------------------------------------------------------------------
__device__ __forceinline__ float block_sum8(float v, float* red, int tid){
    #pragma unroll
    for (int off = 32; off > 0; off >>= 1) v += __shfl_down(v, off);
    __syncthreads();
    if ((tid & 63) == 0) red[tid >> 6] = v;
    __syncthreads();
    float s = 0.f;
    #pragma unroll
    for (int w = 0; w < 8; w++) s += red[w];
    return s;
}

__global__ __launch_bounds__(512) void k_gates(
    const float* __restrict__ wi_raw, const float* __restrict__ wh_raw,
    const float* __restrict__ gi, const float* __restrict__ bi,
    const float* __restrict__ gh, const float* __restrict__ bh,
    const float* __restrict__ gc, const float* __restrict__ bc,
    const float* __restrict__ bias_d, const float* __restrict__ mask_p,
    int t, float* __restrict__ hbuf, float* __restrict__ cbuf,
    float* __restrict__ out_states)
{
    __shared__ float wi_sh[3072], wh_sh[3072], c_sh[768], red[8];
    int b = blockIdx.x, tid = threadIdx.x;
    float m = mask_p[b*TT + t];

    float swi = 0.f, qwi = 0.f, swh = 0.f, qwh = 0.f;
    for (int j = tid; j < 3072; j += 512){
        float a = wi_raw[b*3072 + j];
        float h = wh_raw[b*3072 + j];
        wi_sh[j] = a; wh_sh[j] = h;
        swi += a; qwi += a*a; swh += h; qwh += h*h;
    }
    swi = block_sum8(swi, red, tid);
    qwi = block_sum8(qwi, red, tid);
    swh = block_sum8(swh, red, tid);
    qwh = block_sum8(qwh, red, tid);
    float mi = swi/3072.f, vi = fmaxf((qwi - 3072.f*mi*mi)/3071.f, 0.f);
    float mh = swh/3072.f, vh = fmaxf((qwh - 3072.f*mh*mh)/3071.f, 0.f);
    float ivi = 1.f/(sqrtf(vi + EPSF) + EPSF);
    float ivh = 1.f/(sqrtf(vh + EPSF) + EPSF);

    for (int j = tid; j < 3072; j += 512){
        float pre = m*(gi[j]*(wi_sh[j] - mi)*ivi + bi[j])
                  + m*(gh[j]*(wh_sh[j] - mh)*ivh + bh[j])
                  + bias_d[j];
        wi_sh[j] = pre;
    }
    __syncthreads();

    float sc = 0.f, qc = 0.f;
    for (int u = tid; u < 768; u += 512){
        float f  = wi_sh[u];
        float ig = wi_sh[768 + u];
        float g  = wi_sh[2304 + u];
        float c_old = cbuf[b*768 + u];
        float c1 = fsigmoid(f)*c_old + fsigmoid(ig)*ftanh(g);
        c1 = c1*m + c_old*(1.f - m);
        cbuf[b*768 + u] = c1;
        c_sh[u] = c1;
        sc += c1; qc += c1*c1;
    }
    sc = block_sum8(sc, red, tid);
    qc = block_sum8(qc, red, tid);
    float mc = sc/768.f, vc = fmaxf((qc - 768.f*mc*mc)/767.f, 0.f);
    float ivc = 1.f/(sqrtf(vc + EPSF) + EPSF);

    for (int u = tid; u < 768; u += 512){
        float o = wi_sh[1536 + u];
        float lnc = (gc[u]*(c_sh[u] - mc)*ivc + bc[u])*m;
        float h1 = fsigmoid(o)*ftanh(lnc);
        float h_old = hbuf[b*768 + u];
        h1 = h1*m + h_old*(1.f - m);
        hbuf[b*768 + u] = h1;
        if (out_states) out_states[(size_t)(b*TT + t)*768 + u] = h1;
    }
}

extern "C" void kernel_launch(void* const* d_in, const int* in_sizes, int n_in,
                              void* d_out, int out_size, void* d_ws, size_t ws_size,
                              hipStream_t stream)
{
    (void)in_sizes; (void)n_in; (void)out_size; (void)ws_size;
    const float* input_p = (const float*)d_in[0];
    const float* mask_p  = (const float*)d_in[1];
    const float* input_q = (const float*)d_in[2];
    const float* mask_q  = (const float*)d_in[3];
    const float* W_ih    = (const float*)d_in[4];
    const float* W_hh    = (const float*)d_in[5];
    const float* bias    = (const float*)d_in[6];
    const float* ln_i_g  = (const float*)d_in[7];
    const float* ln_i_b  = (const float*)d_in[8];
    const float* ln_h_g  = (const float*)d_in[9];
    const float* ln_h_b  = (const float*)d_in[10];
    const float* ln_c_g  = (const float*)d_in[11];
    const float* ln_c_b  = (const float*)d_in[12];
    const float* Wq      = (const float*)d_in[13];
    const float* Wp      = (const float*)d_in[14];
    const float* Wr      = (const float*)d_in[15];
    const float* w_att   = (const float*)d_in[16];
    const float* b_att   = (const float*)d_in[17];
    float* out = (float*)d_out;

    float* ws = (float*)d_ws;
    size_t off = 0;
    float* qWq    = ws + off; off += (size_t)NL*BS*TQN*AD;   // 2*16*128*768
    float* pWp0   = ws + off; off += (size_t)BS*TT*AD;       // 16*128*768
    float* pWih0  = ws + off; off += (size_t)BS*TT*H4;       // 16*128*3072
    float* hbuf   = ws + off; off += (size_t)NL*BS*HD;
    float* cbuf   = ws + off; off += (size_t)NL*BS*HD;
    float* s_buf  = ws + off; off += (size_t)BS*AD;
    float* s_buf2 = ws + off; off += (size_t)BS*AD;
    float* wh_raw = ws + off; off += (size_t)BS*H4;
    float* cw_raw = ws + off; off += (size_t)BS*H4;
    float* wghtd  = ws + off; off += (size_t)BS*QD;
    float* wi_raw = ws + off; off += (size_t)BS*H4;

    // zero h and c (contiguous)
    int nzero = 2*NL*BS*HD;
    k_zero<<<(nzero + 255)/256, 256, 0, stream>>>(hbuf, nzero);

    // precompute: qWq (both layers), pWp0, pWih0
    k_mm_pre<<<dim3(12, 128), 256, 0, stream>>>(input_q, Wq,                qWq,                     768, 768);
    k_mm_pre<<<dim3(12, 128), 256, 0, stream>>>(input_q, Wq + 768*768,      qWq + (size_t)2048*768,  768, 768);
    k_mm_pre<<<dim3(12, 128), 256, 0, stream>>>(input_p, Wp,                pWp0,                    768, 768);
    k_mm_pre<<<dim3(48, 128), 256, 0, stream>>>(input_p, W_ih,              pWih0,                   3072, 3072);

    for (int t = 0; t < TT; t++){
        for (int d = 0; d < NL; d++){
            const float* hd  = hbuf + (size_t)d*BS*HD;
            const float* cur = hbuf;  // h[0]; only used when d==1
            k_stage1<<<(d == 0) ? 60 : 120, 256, 0, stream>>>(
                hd, cur,
                Wr + (size_t)d*768*768, Wp + (size_t)768*768,
                W_hh + (size_t)d*768*3072, W_ih + (size_t)d*1536*3072,
                b_att + d*768, pWp0, t, d,
                s_buf, s_buf2, wh_raw, cw_raw);
            k_attn<<<16, 1024, 0, stream>>>(
                s_buf, s_buf2, (d == 1) ? 1 : 0,
                qWq + (size_t)d*BS*TQN*AD, w_att + d*768, mask_q, input_q, wghtd);
            k_stage3<<<48, 256, 0, stream>>>(
                wghtd, W_ih + (size_t)d*1536*3072,
                (d == 0) ? pWih0 : cw_raw, (d == 0) ? 1 : 0, t, wi_raw);
            k_gates<<<16, 512, 0, stream>>>(
                wi_raw, wh_raw,
                ln_i_g + d*3072, ln_i_b + d*3072,
                ln_h_g + d*3072, ln_h_b + d*3072,
                ln_c_g + d*768,  ln_c_b + d*768,
                bias + d*3072, mask_p, t,
                hbuf + (size_t)d*BS*HD, cbuf + (size_t)d*BS*HD,
                (d == NL-1) ? out : nullptr);
        }
    }
    // append mask_p to output
    k_copytail<<<(BS*TT + 255)/256, 256, 0, stream>>>(mask_p, out + (size_t)BS*TT*HD, BS*TT);
}